// Round 10
// baseline (447.688 us; speedup 1.0000x reference)
//
#include <hip/hip_runtime.h>

// MultiHeadAttention B=2,S=2048,E=512,H=8,dh=64 — bf16 MFMA, split-K flash.
// R28: LAUNCH-COUNT reduction, 5 stream ops -> 3. Evidence: non-attn time is
// 117+-3us CONSTANT across r20-r27 while proj/frag/combine were repeatedly
// restructured (r27: 6x less pack-VALU + Kbf roundtrip deleted -> only -2us).
// In-kernel arithmetic (proj ~20us, frag ~3us, combine ~6us) accounts for
// ~35us of 118 => ~80us is dispatch overhead + per-kernel grid-drain.
// Changes:
//  - memset KILLED: flagw[512] (one word per mask tile) written
//    unconditionally by mask pre-tile blocks; attn reads word per kt.
//  - combine FUSED into attn<4>: frag zeroes cnt[512]; each attn block
//    threadfence+syncthreads then tid0 atomicAdd(cnt[bh*32+rb6]); 4th
//    arrival re-reads all splits' Opart/ml (device-scope atomics+fences,
//    G12/G16) and writes out for its 64 rows.
// attn kt-loop byte-identical to r26/r27 (53.2us control).
// EMPIRICAL LAWS: (1) mask loads at USE POINT only; (2) head-pinned XCD map
// bh=(id&7)*2+((id>>3)&1) keeps K/V L2-resident; (3) MFMA fragments from LDS
// or DENSE fragment-major global — never strided; (4) VGPR cap via
// launch_bounds must exceed ~70 or spill; (5) no +32-reg prefetch arrays;
// (6) attn latency floor ~53us in 16x16-frag structure; (7) non-attn time
// is launch-overhead dominated, not kernel-execution dominated.

#define SEQ 2048
#define EMB 512
#define DH  64
#define MROWS 4096
#define NROWS 32768   // 16 heads * 2048 rows
#define L2E 1.4426950408889634f

typedef float  v4f __attribute__((ext_vector_type(4)));
typedef short  v8s __attribute__((ext_vector_type(8)));
typedef __fp16 v2h __attribute__((ext_vector_type(2)));

static __device__ __forceinline__ unsigned int f2bf(float f) {
    unsigned int u = __float_as_uint(f);
    u += 0x7fffu + ((u >> 16) & 1u);       // RNE
    return u >> 16;
}
static __device__ __forceinline__ unsigned int pack2(float a, float b) {
    return f2bf(a) | (f2bf(b) << 16);
}
static __device__ __forceinline__ unsigned int cvtpk(float a, float b) {
    unsigned int r;                        // low16 = bf16(a), high16 = bf16(b), RNE
    asm("v_cvt_pk_bf16_f32 %0, %1, %2" : "=v"(r) : "v"(a), "v"(b));
    return r;
}
static __device__ __forceinline__ unsigned int packh2(float a, float b) {
    v2h h = __builtin_amdgcn_cvt_pkrtz(a, b);
    return __builtin_bit_cast(unsigned int, h);
}

// ---------------------------------------------------------------------------
// Mega kernel: blocks 0..767 = projection (64m x 128n, BK=64, XCD swizzle,
// dense staging; z==0 folds scale*log2e; z==1 emits fragment-major Kfr
// directly); blocks 768..1279 = mask pre-tile (scaled by log2e) + per-tile
// flag word (unconditional write — no memset needed).
// ---------------------------------------------------------------------------
__global__ __launch_bounds__(256, 3) void proj_kernel(
    const float* __restrict__ q, const float* __restrict__ k, const float* __restrict__ v,
    const float* __restrict__ Wq, const float* __restrict__ bq,
    const float* __restrict__ Wk, const float* __restrict__ bk,
    const float* __restrict__ Wv, const float* __restrict__ bv,
    const float* __restrict__ mask,
    unsigned short* __restrict__ Qbf, unsigned short* __restrict__ Kfr,
    unsigned short* __restrict__ Vbf, float* __restrict__ maskT,
    unsigned int* __restrict__ flagw)
{
    __shared__ __align__(16) char smem[27648];   // As 64x144 | Ws 128x144
    const int tid = threadIdx.x;

    // ---- mask pre-tile blocks (independent of projection) ----
    if (blockIdx.x >= 768) {
        const int mb2 = blockIdx.x - 768;
        const int rb = mb2 >> 5, kt = mb2 & 31;
        float* tile = maskT + ((size_t)rb * 32 + kt) * 8192;   // 2048 slots x 4 fp32
        float4 vals[8];
        bool any = false;
#pragma unroll
        for (int i = 0; i < 8; ++i) {
            int s = tid + i * 256;             // 0..2047
            int l  = s & 63;
            int cb = (s >> 6) & 3;
            int g  = (s >> 8) & 1;
            int w2 = (s >> 9) & 3;
            int qd2 = l >> 4, n2 = l & 15;
            vals[i] = *(const float4*)&mask[
                (size_t)(rb * 128 + w2 * 32 + g * 16 + n2) * SEQ + kt * 64 + cb * 16 + qd2 * 4];
            any = any | (vals[i].x != 0.f) | (vals[i].y != 0.f)
                      | (vals[i].z != 0.f) | (vals[i].w != 0.f);
        }
        unsigned int* nzp = (unsigned int*)smem;
        if (tid == 0) *nzp = 0u;
        __syncthreads();
        if (any) *nzp = 1u;                    // benign race (all write 1)
        __syncthreads();
        if (tid == 0) flagw[rb * 32 + kt] = *nzp;   // unconditional (0 or 1)
        if (*nzp) {
#pragma unroll
            for (int i = 0; i < 8; ++i) {
                int s = tid + i * 256;
                vals[i].x *= L2E; vals[i].y *= L2E;   // exp2-domain mask
                vals[i].z *= L2E; vals[i].w *= L2E;
                *(float4*)&tile[(size_t)s * 4] = vals[i];
            }
        }
        return;
    }

    char* As = smem;
    char* Ws = smem + 9216;

    const int id  = blockIdx.x;
    const int pos = id & 31;
    const int nb  = pos >> 3;
    const int unit = (id >> 5) * 8 + (pos & 7);
    const int mb = unit & 63;
    const int z  = unit >> 6;

    const float* A    = (z == 0) ? q  : (z == 1) ? k  : v;
    const float* W    = (z == 0) ? Wq : (z == 1) ? Wk : Wv;
    const float* bias = (z == 0) ? bq : (z == 1) ? bk : bv;
    unsigned short* Cg = (z == 0) ? Qbf : Vbf;   // z==1 writes Kfr (frag-major)

    const int w    = tid >> 6;
    const int lane = tid & 63;
    const int qd   = lane >> 4;
    const int n    = lane & 15;
    const int m0 = mb * 64, n0 = nb * 128;

    float4 areg[4], wreg[8];
#pragma unroll
    for (int i = 0; i < 4; ++i) {
        int c = tid + i * 256;                 // A: 1024 chunks, row=c>>4
        areg[i] = *(const float4*)&A[(size_t)(m0 + (c >> 4)) * EMB + (c & 15) * 4];
    }
#pragma unroll
    for (int i = 0; i < 8; ++i) {
        int c = tid + i * 256;                 // W: 2048 chunks, row=c>>4
        wreg[i] = *(const float4*)&W[(size_t)(n0 + (c >> 4)) * EMB + (c & 15) * 4];
    }

    v4f acc[8];
#pragma unroll
    for (int cb = 0; cb < 8; ++cb) acc[cb] = (v4f)0.f;

#pragma unroll 1
    for (int kt = 0; kt < 8; ++kt) {
        __syncthreads();
#pragma unroll
        for (int i = 0; i < 4; ++i) {
            int c = tid + i * 256;
            uint2 pk = { cvtpk(areg[i].x, areg[i].y), cvtpk(areg[i].z, areg[i].w) };
            *(uint2*)&As[(c >> 4) * 144 + (c & 15) * 8] = pk;
        }
#pragma unroll
        for (int i = 0; i < 8; ++i) {
            int c = tid + i * 256;
            uint2 pk = { cvtpk(wreg[i].x, wreg[i].y), cvtpk(wreg[i].z, wreg[i].w) };
            *(uint2*)&Ws[(c >> 4) * 144 + (c & 15) * 8] = pk;
        }
        __syncthreads();

        if (kt + 1 < 8) {
#pragma unroll
            for (int i = 0; i < 4; ++i) {
                int c = tid + i * 256;
                areg[i] = *(const float4*)&A[(size_t)(m0 + (c >> 4)) * EMB + (kt+1) * 64 + (c & 15) * 4];
            }
#pragma unroll
            for (int i = 0; i < 8; ++i) {
                int c = tid + i * 256;
                wreg[i] = *(const float4*)&W[(size_t)(n0 + (c >> 4)) * EMB + (kt+1) * 64 + (c & 15) * 4];
            }
        }

#pragma unroll
        for (int ks = 0; ks < 2; ++ks) {
            v8s af = *(const v8s*)&As[(w * 16 + n) * 144 + ks * 64 + qd * 16];
#pragma unroll
            for (int cb = 0; cb < 8; ++cb) {
                v8s bfr = *(const v8s*)&Ws[(cb * 16 + n) * 144 + ks * 64 + qd * 16];
                acc[cb] = __builtin_amdgcn_mfma_f32_16x16x32_bf16(af, bfr, acc[cb], 0, 0, 0);
            }
        }
    }

    // z==0: fold scale * log2(e) into Q (exp2-domain scores): 1.4426950409/sqrt(2048)
    const float osc = (z == 0) ? 0.031879357905f : 1.0f;
    float bb[8];
#pragma unroll
    for (int cb = 0; cb < 8; ++cb) bb[cb] = bias[n0 + cb * 16 + n];
#pragma unroll
    for (int cb = 0; cb < 8; ++cb)
#pragma unroll
        for (int r = 0; r < 4; ++r) acc[cb][r] = (acc[cb][r] + bb[cb]) * osc;

    __syncthreads();
    short* Ct = (short*)smem;                  // Ct[64 rows][136 pitch]
#pragma unroll
    for (int cb = 0; cb < 8; ++cb)
#pragma unroll
        for (int r = 0; r < 2; ++r) {
            unsigned int pk = cvtpk(acc[cb][2*r], acc[cb][2*r+1]);
            Ct[(w * 16 + qd * 4 + 2*r)     * 136 + cb * 16 + n] = (short)(pk & 0xffffu);
            Ct[(w * 16 + qd * 4 + 2*r + 1) * 136 + cb * 16 + n] = (short)(pk >> 16);
        }
    __syncthreads();
    const int rr = tid >> 2, q4 = tid & 3;
    if (z == 1) {
        // ---- K: write fragment-major Kfr directly (r27 fusion).
        const int bh = m0 >> 8;                // uniform per block
        const int mm = (m0 & 255) + rr;
        unsigned short* Kh = Kfr + (size_t)bh * 32 * 4096;
#pragma unroll
        for (int i = 0; i < 4; ++i) {
            uint4 t4 = *(const uint4*)&smem[rr * 272 + q4 * 64 + i * 16];
            int nn = n0 + q4 * 32 + i * 8;     // global col
            int s  = mm * 8 + (nn >> 6);
            int kt = s >> 6, sk = s & 63;
            int dd = nn & 63;
            int entry = ((dd >> 5) * 4 + (sk >> 4)) * 64 + ((dd & 31) >> 3) * 16 + (sk & 15);
            *(uint4*)&Kh[(size_t)kt * 4096 + entry * 8] = t4;
        }
    } else {
#pragma unroll
        for (int i = 0; i < 4; ++i) {
            uint4 t4 = *(const uint4*)&smem[rr * 272 + q4 * 64 + i * 16];
            *(uint4*)&Cg[(size_t)(m0 + rr) * EMB + n0 + q4 * 32 + i * 8] = t4;
        }
    }
}

// ---------------------------------------------------------------------------
// Fragment-reorder kernel (V only; K fused into proj): per (bh,kt) 8KB tile,
// emit Vfr[bh][kt][f=ks*4+cb][lane=qd*16+n][8] = V[s=ks*32+qd*8+e][d=cb*16+n].
// Also zeroes cnt[bh*32+kt] for attn's fused combine (runs before attn in
// stream order). Grid (16,32).
// ---------------------------------------------------------------------------
__global__ __launch_bounds__(256) void frag_kernel(
    const unsigned short* __restrict__ Vbf, unsigned short* __restrict__ Vfr,
    unsigned int* __restrict__ cnt)
{
    __shared__ unsigned short T[64 * 136];
    const int bh = blockIdx.x, kt = blockIdx.y;
    const int tid = threadIdx.x;
    if (tid == 0) cnt[bh * 32 + kt] = 0u;      // r28: combine counter reset

    // ---- V: stage transposed tile [d][s], emit fragment-major ----
    const unsigned short* Vh = Vbf + (size_t)bh * (SEQ * DH) + (size_t)kt * 64 * DH;
#pragma unroll
    for (int i = 0; i < 2; ++i) {
        int c = tid + i * 256;
        int s_l = c >> 3, ch = c & 7;
        uint4 t4 = *(const uint4*)&Vh[c * 8];
        const unsigned short* e = (const unsigned short*)&t4;
#pragma unroll
        for (int j = 0; j < 8; ++j)
            T[(ch * 8 + j) * 136 + s_l] = e[j];   // T[d][s]
    }
    __syncthreads();
    unsigned short* Vo = Vfr + ((size_t)bh * 32 + kt) * 4096;
#pragma unroll
    for (int i = 0; i < 2; ++i) {
        int idx = tid + i * 256;
        int f = idx >> 6, l = idx & 63;
        int ks = f >> 2, cb = f & 3, qd = l >> 4, n = l & 15;
        uint4 t4 = *(const uint4*)&T[(cb * 16 + n) * 136 + ks * 32 + qd * 8];
        *(uint4*)&Vo[idx * 8] = t4;
    }
}

// ---------------------------------------------------------------------------
// Flash attention, bf16 MFMA, transposed scores, split-K. kt loop identical
// to r26/r27 (control). R28: SPLITS=4 epilogue fuses the combine — after
// Opart/ml stores, threadfence+sync, tid0 atomicAdd(cnt); the 4th arrival
// for (bh,rb6) re-reads all splits and writes out (64 rows).
// ---------------------------------------------------------------------------
template <int SPLITS>
__global__ __launch_bounds__(256, 6) void attn_kernel(
    const unsigned short* __restrict__ Qbf,
    const unsigned short* __restrict__ Kfr, const unsigned short* __restrict__ Vfr,
    const float* __restrict__ maskT, const float* __restrict__ maskf,
    const unsigned int* __restrict__ flagw, unsigned int* __restrict__ cnt,
    unsigned short* __restrict__ Opart, float* __restrict__ ml,
    float* __restrict__ out)
{
    __shared__ __align__(16) char smem[17408];  // epilogue only: 64x272
    __shared__ unsigned int lastf;
    const int tid  = threadIdx.x;
    const int w    = tid >> 6;
    const int lane = tid & 63;
    const int qd   = lane >> 4;
    const int n    = lane & 15;
    const int a_   = qd & 1;                   // lane bit0 of qd
    const bool diag = (a_ == (qd >> 1));       // qd in {0,3}

    // Head-pinned XCD decomposition: XCD (id&7) owns heads {2x, 2x+1}.
    const int id = blockIdx.x;
    const int bh = (id & 7) * 2 + ((id >> 3) & 1);
    const int unit = id >> 4;                  // SPLITS=4: 0..127; SPLITS=1: 0..31
    const int rb6 = unit & 31;                 // 64-row q block
    const int kq = unit >> 5;
    const int KT0 = kq * (32 / SPLITS), KT1 = KT0 + 32 / SPLITS;

    const unsigned short* Qh  = Qbf + (size_t)bh * (SEQ * DH);
    const unsigned short* Kfh = Kfr + (size_t)bh * 32 * 4096;
    const unsigned short* Vfh = Vfr + (size_t)bh * 32 * 4096;
    const unsigned int* fwb = flagw + (rb6 >> 1) * 32;   // per-kt flag words

    v8s qf[2];
    {
        const size_t qrow = (size_t)(rb6 * 64 + w * 16 + n);
#pragma unroll
        for (int ks = 0; ks < 2; ++ks)
            qf[ks] = *(const v8s*)&Qh[qrow * DH + ks * 32 + qd * 8];
    }

    float l_ = 0.f;
    v4f oacc[4];
#pragma unroll
    for (int cb = 0; cb < 4; ++cb) oacc[cb] = (v4f)0.f;

#pragma unroll 1
    for (int kt = KT0; kt < KT1; ++kt) {
        const unsigned short* Kt = Kfh + (size_t)kt * 4096;
        const unsigned short* Vt = Vfh + (size_t)kt * 4096;

        // ---- mask tile: only load if nonzero (flag word); AT USE POINT
        v4f sacc[4];
        float4 mk[4];
        if (SPLITS > 1) {
            if (fwb[kt] != 0u) {
                const float* tileF = maskT + ((size_t)(rb6 >> 1) * 32 + kt) * 8192;
                const int wg = (rb6 & 1) * 4 + w;   // 16-row group in the 128-row tile
#pragma unroll
                for (int cb = 0; cb < 4; ++cb)
                    sacc[cb] = *(const v4f*)&tileF[
                        (size_t)((wg * 4 + cb) * 64 + qd * 16 + n) * 4];
            } else {
#pragma unroll
                for (int cb = 0; cb < 4; ++cb) sacc[cb] = (v4f)0.f;
            }
        } else {
            const size_t mrow = (size_t)(rb6 * 64 + w * 16 + n);
#pragma unroll
            for (int cb = 0; cb < 4; ++cb) {
                mk[cb] = *(const float4*)&maskf[mrow * SEQ + kt * 64 + cb * 16 + qd * 4];
                sacc[cb] = (v4f)0.f;
            }
        }

        // ---- scores: S^T[s_k][qrow]; K fragments = dense 1KB loads from L2
#pragma unroll
        for (int ks = 0; ks < 2; ++ks)
#pragma unroll
            for (int cb = 0; cb < 4; ++cb) {
                v8s kf = *(const v8s*)&Kt[((ks * 4 + cb) * 64 + lane) * 8];
                sacc[cb] = __builtin_amdgcn_mfma_f32_16x16x32_bf16(kf, qf[ks], sacc[cb], 0, 0, 0);
            }

        // ---- fixed-m softmax (exp2 domain) + in-register P butterfly
        v8s pfr[2];
        {
            float rs = 0.f;
            unsigned int O_[4][2];
#pragma unroll
            for (int cb = 0; cb < 4; ++cb) {
                float s0 = sacc[cb][0], s1 = sacc[cb][1];
                float s2 = sacc[cb][2], s3 = sacc[cb][3];
                if (SPLITS == 1) {
                    s0 = fmaf(mk[cb].x, L2E, s0);
                    s1 = fmaf(mk[cb].y, L2E, s1);
                    s2 = fmaf(mk[cb].z, L2E, s2);
                    s3 = fmaf(mk[cb].w, L2E, s3);
                }
                float e0 = __builtin_amdgcn_exp2f(s0);
                float e1 = __builtin_amdgcn_exp2f(s1);
                float e2 = __builtin_amdgcn_exp2f(s2);
                float e3 = __builtin_amdgcn_exp2f(s3);
                rs += (e0 + e1) + (e2 + e3);
                O_[cb][0] = pack2(e0, e1);
                O_[cb][1] = pack2(e2, e3);
            }
            rs += __shfl_xor(rs, 16);
            rs += __shfl_xor(rs, 32);
            l_ += rs;
#pragma unroll
            for (int ks = 0; ks < 2; ++ks) {
                unsigned int t0 = a_ ? O_[2 * ks][0] : O_[2 * ks + 1][0];
                unsigned int t1 = a_ ? O_[2 * ks][1] : O_[2 * ks + 1][1];
                unsigned int r0 = __shfl_xor(t0, 16);
                unsigned int r1 = __shfl_xor(t1, 16);
                unsigned int Z00 = a_ ? r0 : O_[2 * ks][0];
                unsigned int Z01 = a_ ? r1 : O_[2 * ks][1];
                unsigned int Z10 = a_ ? O_[2 * ks + 1][0] : r0;
                unsigned int Z11 = a_ ? O_[2 * ks + 1][1] : r1;
                unsigned int s00 = __shfl_xor(Z00, 48);
                unsigned int s01 = __shfl_xor(Z01, 48);
                unsigned int s10 = __shfl_xor(Z10, 48);
                unsigned int s11 = __shfl_xor(Z11, 48);
                uint4 pw;
                pw.x = diag ? Z00 : s00;
                pw.y = diag ? Z01 : s01;
                pw.z = diag ? Z10 : s10;
                pw.w = diag ? Z11 : s11;
                pfr[ks] = __builtin_bit_cast(v8s, pw);
            }
        }

        // ---- PV: O^T[d][qrow] += Vt * P^T; V fragments = dense 1KB loads
#pragma unroll
        for (int ks = 0; ks < 2; ++ks)
#pragma unroll
            for (int cb = 0; cb < 4; ++cb) {
                v8s vf = *(const v8s*)&Vt[((ks * 4 + cb) * 64 + lane) * 8];
                oacc[cb] = __builtin_amdgcn_mfma_f32_16x16x32_bf16(vf, pfr[ks], oacc[cb], 0, 0, 0);
            }
    }

    // ---- epilogue
    if (SPLITS == 1) {
        const float inv = 1.0f / l_;
#pragma unroll
        for (int cb = 0; cb < 4; ++cb)
#pragma unroll
            for (int r = 0; r < 4; ++r) oacc[cb][r] *= inv;
    } else {
        if (qd == 0) {   // lanes 0..15 hold l for rows w*16+n (dup across qd)
            const size_t row = (size_t)bh * SEQ + rb6 * 64 + w * 16 + n;
            ml[(size_t)kq * NROWS + row] = l_;
        }
    }
    __syncthreads();
#pragma unroll
    for (int cb = 0; cb < 4; ++cb)
        *(v4f*)&smem[(w * 16 + n) * 272 + cb * 64 + qd * 16] = oacc[cb];
    __syncthreads();
    const int r_l = tid >> 2, q4 = tid & 3;    // 64 rows, 4 threads/row
    if (SPLITS == 1) {
        float* dst = &out[((size_t)bh * SEQ + rb6 * 64 + r_l) * DH + q4 * 16];
#pragma unroll
        for (int i = 0; i < 4; ++i) {
            float4 t4 = *(const float4*)&smem[r_l * 272 + q4 * 64 + i * 16];
            *(float4*)&dst[i * 4] = t4;
        }
    } else {
        unsigned short* dst = &Opart[((size_t)kq * NROWS + (size_t)bh * SEQ + rb6 * 64 + r_l) * DH + q4 * 16];
#pragma unroll
        for (int i = 0; i < 2; ++i) {
            float4 f0 = *(const float4*)&smem[r_l * 272 + q4 * 64 + i * 32];
            float4 f1 = *(const float4*)&smem[r_l * 272 + q4 * 64 + i * 32 + 16];
            uint4 o = { packh2(f0.x, f0.y), packh2(f0.z, f0.w),
                        packh2(f1.x, f1.y), packh2(f1.z, f1.w) };
            *(uint4*)&dst[i * 8] = o;
        }

        // ---- r28 fused combine: last split-block for (bh,rb6) reduces.
        __threadfence();                       // publish Opart+ml (device scope)
        __syncthreads();                       // all threads fenced before count
        if (tid == 0)
            lastf = (atomicAdd(&cnt[bh * 32 + rb6], 1u) == 3u) ? 1u : 0u;
        __syncthreads();
        if (lastf) {
            __threadfence();                   // acquire: see other splits' writes
            const int d0 = (tid & 3) * 16;     // 16 d per thread, 4 threads/row
            const size_t row = (size_t)bh * SEQ + rb6 * 64 + r_l;
            float denom = 0.f;
            float a[16];
#pragma unroll
            for (int i = 0; i < 16; ++i) a[i] = 0.f;
#pragma unroll 1
            for (int s = 0; s < 4; ++s) {
                denom += ml[(size_t)s * NROWS + row];
                const uint2* op = (const uint2*)&Opart[((size_t)s * NROWS + row) * DH + d0];
#pragma unroll
                for (int j = 0; j < 4; ++j) {
                    uint2 u = op[j];
                    v2h h0 = __builtin_bit_cast(v2h, u.x);
                    v2h h1 = __builtin_bit_cast(v2h, u.y);
                    a[j*4+0] += (float)h0.x; a[j*4+1] += (float)h0.y;
                    a[j*4+2] += (float)h1.x; a[j*4+3] += (float)h1.y;
                }
            }
            const float inv = 1.0f / denom;
            float4* dstf = (float4*)&out[row * DH + d0];
#pragma unroll
            for (int j = 0; j < 4; ++j)
                dstf[j] = make_float4(a[j*4]*inv, a[j*4+1]*inv, a[j*4+2]*inv, a[j*4+3]*inv);
        }
    }
}

extern "C" void kernel_launch(void* const* d_in, const int* in_sizes, int n_in,
                              void* d_out, int out_size, void* d_ws, size_t ws_size,
                              hipStream_t stream) {
    const float* q    = (const float*)d_in[0];
    const float* k    = (const float*)d_in[1];
    const float* v    = (const float*)d_in[2];
    const float* mask = (const float*)d_in[3];
    const float* Wq   = (const float*)d_in[4];
    const float* bq   = (const float*)d_in[5];
    const float* Wk   = (const float*)d_in[6];
    const float* bk   = (const float*)d_in[7];
    const float* Wv   = (const float*)d_in[8];
    const float* bv   = (const float*)d_in[9];

    char* ws = (char*)d_ws;
    const size_t MB = 1024 * 1024;
    unsigned short* Qbf   = (unsigned short*)(ws + 0);         //  0..4  MB
    unsigned short* Vfr   = (unsigned short*)(ws + 8 * MB);    //  8..12 MB (frag-major V)
    unsigned short* Opart = (unsigned short*)(ws + 12 * MB);   // 12..28 MB (fp16)
    unsigned short* Vbf   = (unsigned short*)(ws + 12 * MB);   // overlay, dead after frag
    float*          mlp   = (float*)(ws + 28 * MB);            // 28..28.5 MB (512 KB used)
    unsigned int*   flagw = (unsigned int*)(ws + 28 * MB + 512 * 1024);  // 2 KB
    unsigned int*   cnt   = (unsigned int*)(ws + 28 * MB + 520 * 1024);  // 2 KB
    float*          maskT = (float*)(ws + 29 * MB);            // 29..45 MB (fp32)

    const size_t need_split = 49 * MB;                         // ws >= 49 MB proven (r4)
    const bool do_split = ws_size >= need_split;

    if (do_split) {
        unsigned short* Kfr = (unsigned short*)(ws + 45 * MB); // 45..49 MB (frag-major K)
        proj_kernel<<<1280, 256, 0, stream>>>(q, k, v, Wq, bq, Wk, bk, Wv, bv,
                                              mask, Qbf, Kfr, Vbf, maskT, flagw);
        dim3 tgrid(16, 32);
        frag_kernel<<<tgrid, 256, 0, stream>>>(Vbf, Vfr, cnt);
        attn_kernel<4><<<2048, 256, 0, stream>>>(Qbf, Kfr, Vfr, maskT, mask, flagw,
                                                 cnt, Opart, mlp, (float*)d_out);
    } else {
        unsigned short* Kfr = (unsigned short*)(ws + 16 * MB); // 16..20 MB (Opart unused)
        proj_kernel<<<768, 256, 0, stream>>>(q, k, v, Wq, bq, Wk, bk, Wv, bv,
                                             mask, Qbf, Kfr, Vbf, maskT, flagw);
        dim3 tgrid(16, 32);
        frag_kernel<<<tgrid, 256, 0, stream>>>(Vbf, Vfr, cnt);
        attn_kernel<1><<<512, 256, 0, stream>>>(Qbf, Kfr, Vfr, maskT, mask, flagw,
                                                cnt, Opart, mlp, (float*)d_out);
    }
}

// Round 11
// 166.716 us; speedup vs baseline: 2.6853x; 2.6853x over previous
//
#include <hip/hip_runtime.h>

// MultiHeadAttention B=2,S=2048,E=512,H=8,dh=64 — bf16 MFMA, split-K flash.
// R29 = r27 structure restored (session best 171.0us) + r28's two safe bits.
// R28 post-mortem: fusing combine into attn via __threadfence+atomic
// rendezvous poisoned the WHOLE attn kernel (53->350us, MfmaUtil 1.9%,
// HBM 165GB/s) — LAW 8: no device-scope fences/atomic rendezvous inside the
// attn hot kernel; kernel boundaries are the cheap ordering for Opart->
// combine. Kept from r28: flagw[512] unconditional flag words (memset
// launch deleted — benign: plain store in proj, scalar load in attn).
// Kept from r27: cvt_pk packing in proj; frag-major Kfr written directly
// from proj epilogue (Kbf roundtrip + frag K-half deleted).
// attn kt-loop byte-identical to r26/r27 (53.1-53.2us, VGPR 40, FETCH 6.2MB,
// conflicts 0).
// EMPIRICAL LAWS: (1) mask loads at USE POINT only; (2) head-pinned XCD map
// bh=(id&7)*2+((id>>3)&1) keeps K/V L2-resident; (3) MFMA fragments from LDS
// or DENSE fragment-major global — never strided; (4) VGPR cap via
// launch_bounds must exceed ~70 or spill; (5) no +32-reg prefetch arrays;
// (6) attn latency floor ~53us in 16x16-frag structure; (7) non-attn ~117us
// barely moved by in-kernel proj/frag/combine changes; (8) no device-scope
// fences in hot kernels.

#define SEQ 2048
#define EMB 512
#define DH  64
#define MROWS 4096
#define NROWS 32768   // 16 heads * 2048 rows
#define L2E 1.4426950408889634f

typedef float  v4f __attribute__((ext_vector_type(4)));
typedef short  v8s __attribute__((ext_vector_type(8)));
typedef __fp16 v2h __attribute__((ext_vector_type(2)));

static __device__ __forceinline__ unsigned int f2bf(float f) {
    unsigned int u = __float_as_uint(f);
    u += 0x7fffu + ((u >> 16) & 1u);       // RNE
    return u >> 16;
}
static __device__ __forceinline__ unsigned int pack2(float a, float b) {
    return f2bf(a) | (f2bf(b) << 16);
}
static __device__ __forceinline__ unsigned int cvtpk(float a, float b) {
    unsigned int r;                        // low16 = bf16(a), high16 = bf16(b), RNE
    asm("v_cvt_pk_bf16_f32 %0, %1, %2" : "=v"(r) : "v"(a), "v"(b));
    return r;
}
static __device__ __forceinline__ unsigned int packh2(float a, float b) {
    v2h h = __builtin_amdgcn_cvt_pkrtz(a, b);
    return __builtin_bit_cast(unsigned int, h);
}

// ---------------------------------------------------------------------------
// Mega kernel: blocks 0..767 = projection (64m x 128n, BK=64, XCD swizzle,
// dense staging; z==0 folds scale*log2e; z==1 emits fragment-major Kfr
// directly); blocks 768..1279 = mask pre-tile (scaled by log2e) + per-tile
// flag word (unconditional write — no memset needed).
// ---------------------------------------------------------------------------
__global__ __launch_bounds__(256, 3) void proj_kernel(
    const float* __restrict__ q, const float* __restrict__ k, const float* __restrict__ v,
    const float* __restrict__ Wq, const float* __restrict__ bq,
    const float* __restrict__ Wk, const float* __restrict__ bk,
    const float* __restrict__ Wv, const float* __restrict__ bv,
    const float* __restrict__ mask,
    unsigned short* __restrict__ Qbf, unsigned short* __restrict__ Kfr,
    unsigned short* __restrict__ Vbf, float* __restrict__ maskT,
    unsigned int* __restrict__ flagw)
{
    __shared__ __align__(16) char smem[27648];   // As 64x144 | Ws 128x144
    const int tid = threadIdx.x;

    // ---- mask pre-tile blocks (independent of projection) ----
    if (blockIdx.x >= 768) {
        const int mb2 = blockIdx.x - 768;
        const int rb = mb2 >> 5, kt = mb2 & 31;
        float* tile = maskT + ((size_t)rb * 32 + kt) * 8192;   // 2048 slots x 4 fp32
        float4 vals[8];
        bool any = false;
#pragma unroll
        for (int i = 0; i < 8; ++i) {
            int s = tid + i * 256;             // 0..2047
            int l  = s & 63;
            int cb = (s >> 6) & 3;
            int g  = (s >> 8) & 1;
            int w2 = (s >> 9) & 3;
            int qd2 = l >> 4, n2 = l & 15;
            vals[i] = *(const float4*)&mask[
                (size_t)(rb * 128 + w2 * 32 + g * 16 + n2) * SEQ + kt * 64 + cb * 16 + qd2 * 4];
            any = any | (vals[i].x != 0.f) | (vals[i].y != 0.f)
                      | (vals[i].z != 0.f) | (vals[i].w != 0.f);
        }
        unsigned int* nzp = (unsigned int*)smem;
        if (tid == 0) *nzp = 0u;
        __syncthreads();
        if (any) *nzp = 1u;                    // benign race (all write 1)
        __syncthreads();
        if (tid == 0) flagw[rb * 32 + kt] = *nzp;   // unconditional (0 or 1)
        if (*nzp) {
#pragma unroll
            for (int i = 0; i < 8; ++i) {
                int s = tid + i * 256;
                vals[i].x *= L2E; vals[i].y *= L2E;   // exp2-domain mask
                vals[i].z *= L2E; vals[i].w *= L2E;
                *(float4*)&tile[(size_t)s * 4] = vals[i];
            }
        }
        return;
    }

    char* As = smem;
    char* Ws = smem + 9216;

    const int id  = blockIdx.x;
    const int pos = id & 31;
    const int nb  = pos >> 3;
    const int unit = (id >> 5) * 8 + (pos & 7);
    const int mb = unit & 63;
    const int z  = unit >> 6;

    const float* A    = (z == 0) ? q  : (z == 1) ? k  : v;
    const float* W    = (z == 0) ? Wq : (z == 1) ? Wk : Wv;
    const float* bias = (z == 0) ? bq : (z == 1) ? bk : bv;
    unsigned short* Cg = (z == 0) ? Qbf : Vbf;   // z==1 writes Kfr (frag-major)

    const int w    = tid >> 6;
    const int lane = tid & 63;
    const int qd   = lane >> 4;
    const int n    = lane & 15;
    const int m0 = mb * 64, n0 = nb * 128;

    float4 areg[4], wreg[8];
#pragma unroll
    for (int i = 0; i < 4; ++i) {
        int c = tid + i * 256;                 // A: 1024 chunks, row=c>>4
        areg[i] = *(const float4*)&A[(size_t)(m0 + (c >> 4)) * EMB + (c & 15) * 4];
    }
#pragma unroll
    for (int i = 0; i < 8; ++i) {
        int c = tid + i * 256;                 // W: 2048 chunks, row=c>>4
        wreg[i] = *(const float4*)&W[(size_t)(n0 + (c >> 4)) * EMB + (c & 15) * 4];
    }

    v4f acc[8];
#pragma unroll
    for (int cb = 0; cb < 8; ++cb) acc[cb] = (v4f)0.f;

#pragma unroll 1
    for (int kt = 0; kt < 8; ++kt) {
        __syncthreads();
#pragma unroll
        for (int i = 0; i < 4; ++i) {
            int c = tid + i * 256;
            uint2 pk = { cvtpk(areg[i].x, areg[i].y), cvtpk(areg[i].z, areg[i].w) };
            *(uint2*)&As[(c >> 4) * 144 + (c & 15) * 8] = pk;
        }
#pragma unroll
        for (int i = 0; i < 8; ++i) {
            int c = tid + i * 256;
            uint2 pk = { cvtpk(wreg[i].x, wreg[i].y), cvtpk(wreg[i].z, wreg[i].w) };
            *(uint2*)&Ws[(c >> 4) * 144 + (c & 15) * 8] = pk;
        }
        __syncthreads();

        if (kt + 1 < 8) {
#pragma unroll
            for (int i = 0; i < 4; ++i) {
                int c = tid + i * 256;
                areg[i] = *(const float4*)&A[(size_t)(m0 + (c >> 4)) * EMB + (kt+1) * 64 + (c & 15) * 4];
            }
#pragma unroll
            for (int i = 0; i < 8; ++i) {
                int c = tid + i * 256;
                wreg[i] = *(const float4*)&W[(size_t)(n0 + (c >> 4)) * EMB + (kt+1) * 64 + (c & 15) * 4];
            }
        }

#pragma unroll
        for (int ks = 0; ks < 2; ++ks) {
            v8s af = *(const v8s*)&As[(w * 16 + n) * 144 + ks * 64 + qd * 16];
#pragma unroll
            for (int cb = 0; cb < 8; ++cb) {
                v8s bfr = *(const v8s*)&Ws[(cb * 16 + n) * 144 + ks * 64 + qd * 16];
                acc[cb] = __builtin_amdgcn_mfma_f32_16x16x32_bf16(af, bfr, acc[cb], 0, 0, 0);
            }
        }
    }

    // z==0: fold scale * log2(e) into Q (exp2-domain scores): 1.4426950409/sqrt(2048)
    const float osc = (z == 0) ? 0.031879357905f : 1.0f;
    float bb[8];
#pragma unroll
    for (int cb = 0; cb < 8; ++cb) bb[cb] = bias[n0 + cb * 16 + n];
#pragma unroll
    for (int cb = 0; cb < 8; ++cb)
#pragma unroll
        for (int r = 0; r < 4; ++r) acc[cb][r] = (acc[cb][r] + bb[cb]) * osc;

    __syncthreads();
    short* Ct = (short*)smem;                  // Ct[64 rows][136 pitch]
#pragma unroll
    for (int cb = 0; cb < 8; ++cb)
#pragma unroll
        for (int r = 0; r < 2; ++r) {
            unsigned int pk = cvtpk(acc[cb][2*r], acc[cb][2*r+1]);
            Ct[(w * 16 + qd * 4 + 2*r)     * 136 + cb * 16 + n] = (short)(pk & 0xffffu);
            Ct[(w * 16 + qd * 4 + 2*r + 1) * 136 + cb * 16 + n] = (short)(pk >> 16);
        }
    __syncthreads();
    const int rr = tid >> 2, q4 = tid & 3;
    if (z == 1) {
        // ---- K: write fragment-major Kfr directly (r27 fusion).
        const int bh = m0 >> 8;                // uniform per block
        const int mm = (m0 & 255) + rr;
        unsigned short* Kh = Kfr + (size_t)bh * 32 * 4096;
#pragma unroll
        for (int i = 0; i < 4; ++i) {
            uint4 t4 = *(const uint4*)&smem[rr * 272 + q4 * 64 + i * 16];
            int nn = n0 + q4 * 32 + i * 8;     // global col
            int s  = mm * 8 + (nn >> 6);
            int kt = s >> 6, sk = s & 63;
            int dd = nn & 63;
            int entry = ((dd >> 5) * 4 + (sk >> 4)) * 64 + ((dd & 31) >> 3) * 16 + (sk & 15);
            *(uint4*)&Kh[(size_t)kt * 4096 + entry * 8] = t4;
        }
    } else {
#pragma unroll
        for (int i = 0; i < 4; ++i) {
            uint4 t4 = *(const uint4*)&smem[rr * 272 + q4 * 64 + i * 16];
            *(uint4*)&Cg[(size_t)(m0 + rr) * EMB + n0 + q4 * 32 + i * 8] = t4;
        }
    }
}

// ---------------------------------------------------------------------------
// Fragment-reorder kernel (V only; K fused into proj): per (bh,kt) 8KB tile,
// emit Vfr[bh][kt][f=ks*4+cb][lane=qd*16+n][8] = V[s=ks*32+qd*8+e][d=cb*16+n].
// Grid (16,32).
// ---------------------------------------------------------------------------
__global__ __launch_bounds__(256) void frag_kernel(
    const unsigned short* __restrict__ Vbf, unsigned short* __restrict__ Vfr)
{
    __shared__ unsigned short T[64 * 136];
    const int bh = blockIdx.x, kt = blockIdx.y;
    const int tid = threadIdx.x;

    // ---- V: stage transposed tile [d][s], emit fragment-major ----
    const unsigned short* Vh = Vbf + (size_t)bh * (SEQ * DH) + (size_t)kt * 64 * DH;
#pragma unroll
    for (int i = 0; i < 2; ++i) {
        int c = tid + i * 256;
        int s_l = c >> 3, ch = c & 7;
        uint4 t4 = *(const uint4*)&Vh[c * 8];
        const unsigned short* e = (const unsigned short*)&t4;
#pragma unroll
        for (int j = 0; j < 8; ++j)
            T[(ch * 8 + j) * 136 + s_l] = e[j];   // T[d][s]
    }
    __syncthreads();
    unsigned short* Vo = Vfr + ((size_t)bh * 32 + kt) * 4096;
#pragma unroll
    for (int i = 0; i < 2; ++i) {
        int idx = tid + i * 256;
        int f = idx >> 6, l = idx & 63;
        int ks = f >> 2, cb = f & 3, qd = l >> 4, n = l & 15;
        uint4 t4 = *(const uint4*)&T[(cb * 16 + n) * 136 + ks * 32 + qd * 8];
        *(uint4*)&Vo[idx * 8] = t4;
    }
}

// ---------------------------------------------------------------------------
// Flash attention, bf16 MFMA, transposed scores, split-K. kt loop identical
// to r26/r27 (53.1-53.2us verified). 64 q-rows/block, NO LDS in loop,
// frag-major K/V loads at use, in-register P butterfly, exp2 softmax,
// (256,6). Mask tile AT USE POINT, gated by flagw word. NO fences (law 8).
// ---------------------------------------------------------------------------
template <int SPLITS>
__global__ __launch_bounds__(256, 6) void attn_kernel(
    const unsigned short* __restrict__ Qbf,
    const unsigned short* __restrict__ Kfr, const unsigned short* __restrict__ Vfr,
    const float* __restrict__ maskT, const float* __restrict__ maskf,
    const unsigned int* __restrict__ flagw,
    unsigned short* __restrict__ Opart, float* __restrict__ ml,
    float* __restrict__ out)
{
    __shared__ __align__(16) char smem[17408];  // epilogue only: 64x272
    const int tid  = threadIdx.x;
    const int w    = tid >> 6;
    const int lane = tid & 63;
    const int qd   = lane >> 4;
    const int n    = lane & 15;
    const int a_   = qd & 1;                   // lane bit0 of qd
    const bool diag = (a_ == (qd >> 1));       // qd in {0,3}

    // Head-pinned XCD decomposition: XCD (id&7) owns heads {2x, 2x+1}.
    const int id = blockIdx.x;
    const int bh = (id & 7) * 2 + ((id >> 3) & 1);
    const int unit = id >> 4;                  // SPLITS=4: 0..127; SPLITS=1: 0..31
    const int rb6 = unit & 31;                 // 64-row q block
    const int kq = unit >> 5;
    const int KT0 = kq * (32 / SPLITS), KT1 = KT0 + 32 / SPLITS;

    const unsigned short* Qh  = Qbf + (size_t)bh * (SEQ * DH);
    const unsigned short* Kfh = Kfr + (size_t)bh * 32 * 4096;
    const unsigned short* Vfh = Vfr + (size_t)bh * 32 * 4096;
    const unsigned int* fwb = flagw + (rb6 >> 1) * 32;   // per-kt flag words

    v8s qf[2];
    {
        const size_t qrow = (size_t)(rb6 * 64 + w * 16 + n);
#pragma unroll
        for (int ks = 0; ks < 2; ++ks)
            qf[ks] = *(const v8s*)&Qh[qrow * DH + ks * 32 + qd * 8];
    }

    float l_ = 0.f;
    v4f oacc[4];
#pragma unroll
    for (int cb = 0; cb < 4; ++cb) oacc[cb] = (v4f)0.f;

#pragma unroll 1
    for (int kt = KT0; kt < KT1; ++kt) {
        const unsigned short* Kt = Kfh + (size_t)kt * 4096;
        const unsigned short* Vt = Vfh + (size_t)kt * 4096;

        // ---- mask tile: only load if nonzero (flag word); AT USE POINT
        v4f sacc[4];
        float4 mk[4];
        if (SPLITS > 1) {
            if (fwb[kt] != 0u) {
                const float* tileF = maskT + ((size_t)(rb6 >> 1) * 32 + kt) * 8192;
                const int wg = (rb6 & 1) * 4 + w;   // 16-row group in the 128-row tile
#pragma unroll
                for (int cb = 0; cb < 4; ++cb)
                    sacc[cb] = *(const v4f*)&tileF[
                        (size_t)((wg * 4 + cb) * 64 + qd * 16 + n) * 4];
            } else {
#pragma unroll
                for (int cb = 0; cb < 4; ++cb) sacc[cb] = (v4f)0.f;
            }
        } else {
            const size_t mrow = (size_t)(rb6 * 64 + w * 16 + n);
#pragma unroll
            for (int cb = 0; cb < 4; ++cb) {
                mk[cb] = *(const float4*)&maskf[mrow * SEQ + kt * 64 + cb * 16 + qd * 4];
                sacc[cb] = (v4f)0.f;
            }
        }

        // ---- scores: S^T[s_k][qrow]; K fragments = dense 1KB loads from L2
#pragma unroll
        for (int ks = 0; ks < 2; ++ks)
#pragma unroll
            for (int cb = 0; cb < 4; ++cb) {
                v8s kf = *(const v8s*)&Kt[((ks * 4 + cb) * 64 + lane) * 8];
                sacc[cb] = __builtin_amdgcn_mfma_f32_16x16x32_bf16(kf, qf[ks], sacc[cb], 0, 0, 0);
            }

        // ---- fixed-m softmax (exp2 domain) + in-register P butterfly
        v8s pfr[2];
        {
            float rs = 0.f;
            unsigned int O_[4][2];
#pragma unroll
            for (int cb = 0; cb < 4; ++cb) {
                float s0 = sacc[cb][0], s1 = sacc[cb][1];
                float s2 = sacc[cb][2], s3 = sacc[cb][3];
                if (SPLITS == 1) {
                    s0 = fmaf(mk[cb].x, L2E, s0);
                    s1 = fmaf(mk[cb].y, L2E, s1);
                    s2 = fmaf(mk[cb].z, L2E, s2);
                    s3 = fmaf(mk[cb].w, L2E, s3);
                }
                float e0 = __builtin_amdgcn_exp2f(s0);
                float e1 = __builtin_amdgcn_exp2f(s1);
                float e2 = __builtin_amdgcn_exp2f(s2);
                float e3 = __builtin_amdgcn_exp2f(s3);
                rs += (e0 + e1) + (e2 + e3);
                O_[cb][0] = pack2(e0, e1);
                O_[cb][1] = pack2(e2, e3);
            }
            rs += __shfl_xor(rs, 16);
            rs += __shfl_xor(rs, 32);
            l_ += rs;
#pragma unroll
            for (int ks = 0; ks < 2; ++ks) {
                unsigned int t0 = a_ ? O_[2 * ks][0] : O_[2 * ks + 1][0];
                unsigned int t1 = a_ ? O_[2 * ks][1] : O_[2 * ks + 1][1];
                unsigned int r0 = __shfl_xor(t0, 16);
                unsigned int r1 = __shfl_xor(t1, 16);
                unsigned int Z00 = a_ ? r0 : O_[2 * ks][0];
                unsigned int Z01 = a_ ? r1 : O_[2 * ks][1];
                unsigned int Z10 = a_ ? O_[2 * ks + 1][0] : r0;
                unsigned int Z11 = a_ ? O_[2 * ks + 1][1] : r1;
                unsigned int s00 = __shfl_xor(Z00, 48);
                unsigned int s01 = __shfl_xor(Z01, 48);
                unsigned int s10 = __shfl_xor(Z10, 48);
                unsigned int s11 = __shfl_xor(Z11, 48);
                uint4 pw;
                pw.x = diag ? Z00 : s00;
                pw.y = diag ? Z01 : s01;
                pw.z = diag ? Z10 : s10;
                pw.w = diag ? Z11 : s11;
                pfr[ks] = __builtin_bit_cast(v8s, pw);
            }
        }

        // ---- PV: O^T[d][qrow] += Vt * P^T; V fragments = dense 1KB loads
#pragma unroll
        for (int ks = 0; ks < 2; ++ks)
#pragma unroll
            for (int cb = 0; cb < 4; ++cb) {
                v8s vf = *(const v8s*)&Vt[((ks * 4 + cb) * 64 + lane) * 8];
                oacc[cb] = __builtin_amdgcn_mfma_f32_16x16x32_bf16(vf, pfr[ks], oacc[cb], 0, 0, 0);
            }
    }

    // ---- epilogue
    if (SPLITS == 1) {
        const float inv = 1.0f / l_;
#pragma unroll
        for (int cb = 0; cb < 4; ++cb)
#pragma unroll
            for (int r = 0; r < 4; ++r) oacc[cb][r] *= inv;
    } else {
        if (qd == 0) {   // lanes 0..15 hold l for rows w*16+n (dup across qd)
            const size_t row = (size_t)bh * SEQ + rb6 * 64 + w * 16 + n;
            ml[(size_t)kq * NROWS + row] = l_;
        }
    }
    __syncthreads();
#pragma unroll
    for (int cb = 0; cb < 4; ++cb)
        *(v4f*)&smem[(w * 16 + n) * 272 + cb * 64 + qd * 16] = oacc[cb];
    __syncthreads();
    const int r_l = tid >> 2, q4 = tid & 3;    // 64 rows, 4 threads/row
    if (SPLITS == 1) {
        float* dst = &out[((size_t)bh * SEQ + rb6 * 64 + r_l) * DH + q4 * 16];
#pragma unroll
        for (int i = 0; i < 4; ++i) {
            float4 t4 = *(const float4*)&smem[r_l * 272 + q4 * 64 + i * 16];
            *(float4*)&dst[i * 4] = t4;
        }
    } else {
        unsigned short* dst = &Opart[((size_t)kq * NROWS + (size_t)bh * SEQ + rb6 * 64 + r_l) * DH + q4 * 16];
#pragma unroll
        for (int i = 0; i < 2; ++i) {
            float4 f0 = *(const float4*)&smem[r_l * 272 + q4 * 64 + i * 32];
            float4 f1 = *(const float4*)&smem[r_l * 272 + q4 * 64 + i * 32 + 16];
            uint4 o = { packh2(f0.x, f0.y), packh2(f0.z, f0.w),
                        packh2(f1.x, f1.y), packh2(f1.z, f1.w) };
            *(uint4*)&dst[i * 8] = o;
        }
    }
}

// ---------------------------------------------------------------------------
// Combine split-K partials (Opart fp16): out = sum_s O_s / sum_s l_s.
// ---------------------------------------------------------------------------
__global__ __launch_bounds__(256) void combine_kernel(
    const unsigned int* __restrict__ Opart, const float* __restrict__ ml,
    float* __restrict__ out, int splits)
{
    const int tid = threadIdx.x;
    const size_t row = (size_t)blockIdx.x * 16 + (tid >> 4);
    const int d4 = (tid & 15) * 4;
    float denom = 0.f;
    float4 o = make_float4(0.f, 0.f, 0.f, 0.f);
    for (int s = 0; s < splits; ++s) {
        denom += ml[(size_t)s * NROWS + row];
        uint2 u = *(const uint2*)&Opart[((size_t)s * NROWS + row) * 32 + (d4 >> 1)];
        v2h h0 = __builtin_bit_cast(v2h, u.x);
        v2h h1 = __builtin_bit_cast(v2h, u.y);
        o.x += (float)h0.x; o.y += (float)h0.y;
        o.z += (float)h1.x; o.w += (float)h1.y;
    }
    const float inv = 1.0f / denom;
    o.x *= inv; o.y *= inv; o.z *= inv; o.w *= inv;
    *(float4*)&out[row * DH + d4] = o;
}

extern "C" void kernel_launch(void* const* d_in, const int* in_sizes, int n_in,
                              void* d_out, int out_size, void* d_ws, size_t ws_size,
                              hipStream_t stream) {
    const float* q    = (const float*)d_in[0];
    const float* k    = (const float*)d_in[1];
    const float* v    = (const float*)d_in[2];
    const float* mask = (const float*)d_in[3];
    const float* Wq   = (const float*)d_in[4];
    const float* bq   = (const float*)d_in[5];
    const float* Wk   = (const float*)d_in[6];
    const float* bk   = (const float*)d_in[7];
    const float* Wv   = (const float*)d_in[8];
    const float* bv   = (const float*)d_in[9];

    char* ws = (char*)d_ws;
    const size_t MB = 1024 * 1024;
    unsigned short* Qbf   = (unsigned short*)(ws + 0);         //  0..4  MB
    unsigned short* Vfr   = (unsigned short*)(ws + 8 * MB);    //  8..12 MB (frag-major V)
    unsigned short* Opart = (unsigned short*)(ws + 12 * MB);   // 12..28 MB (fp16)
    unsigned short* Vbf   = (unsigned short*)(ws + 12 * MB);   // overlay, dead after frag
    float*          mlp   = (float*)(ws + 28 * MB);            // 28..28.5 MB (512 KB used)
    unsigned int*   flagw = (unsigned int*)(ws + 28 * MB + 512 * 1024);  // 2 KB
    float*          maskT = (float*)(ws + 29 * MB);            // 29..45 MB (fp32)

    const size_t need_split = 49 * MB;                         // ws >= 49 MB proven (r4)
    const bool do_split = ws_size >= need_split;

    if (do_split) {
        unsigned short* Kfr = (unsigned short*)(ws + 45 * MB); // 45..49 MB (frag-major K)
        proj_kernel<<<1280, 256, 0, stream>>>(q, k, v, Wq, bq, Wk, bk, Wv, bv,
                                              mask, Qbf, Kfr, Vbf, maskT, flagw);
        dim3 tgrid(16, 32);
        frag_kernel<<<tgrid, 256, 0, stream>>>(Vbf, Vfr);
        attn_kernel<4><<<2048, 256, 0, stream>>>(Qbf, Kfr, Vfr, maskT, mask, flagw,
                                                 Opart, mlp, (float*)d_out);
        combine_kernel<<<NROWS / 16, 256, 0, stream>>>((const unsigned int*)Opart,
                                                       mlp, (float*)d_out, 4);
    } else {
        unsigned short* Kfr = (unsigned short*)(ws + 16 * MB); // 16..20 MB (Opart unused)
        proj_kernel<<<768, 256, 0, stream>>>(q, k, v, Wq, bq, Wk, bk, Wv, bv,
                                             mask, Qbf, Kfr, Vbf, maskT, flagw);
        dim3 tgrid(16, 32);
        frag_kernel<<<tgrid, 256, 0, stream>>>(Vbf, Vfr);
        attn_kernel<1><<<512, 256, 0, stream>>>(Qbf, Kfr, Vfr, maskT, mask, flagw,
                                                Opart, mlp, (float*)d_out);
    }
}